// Round 11
// baseline (471.581 us; speedup 1.0000x reference)
//
#include <hip/hip_runtime.h>
#include <hip/hip_bf16.h>

typedef __attribute__((ext_vector_type(8))) short short8;
typedef __attribute__((ext_vector_type(4))) short short4v;
typedef __attribute__((ext_vector_type(4))) float f32x4;

#define MFMA(a, b, c) __builtin_amdgcn_mfma_f32_16x16x32_bf16(a, b, c, 0, 0, 0)
// XOR-swizzled [64][256] bf16 LDS index (8-elem granule)
#define XS(t, c) (((t) << 8) + ((c) ^ (((t) & 7) << 3)))

__device__ __forceinline__ unsigned int pk2(float lo, float hi) {
    union { __hip_bfloat162 h2; unsigned int u; } cv;
    cv.h2 = __float22bfloat162_rn(make_float2(lo, hi));
    return cv.u;
}

__device__ __forceinline__ unsigned short f2bf1(float f) {
    unsigned int u = __float_as_uint(f);
    u += 0x7FFFu + ((u >> 16) & 1u);
    return (unsigned short)(u >> 16);
}

__device__ __forceinline__ short4v u2s4(uint2 p) {
    union { uint2 u; short4v s; } t; t.u = p; return t.s;
}

#if __has_builtin(__builtin_amdgcn_mfma_f32_16x16x16bf16_1k)
__device__ __forceinline__ f32x4 mfma16(uint2 a, uint2 b, f32x4 c) {
    return __builtin_amdgcn_mfma_f32_16x16x16bf16_1k(u2s4(a), u2s4(b), c, 0, 0, 0);
}
#else
__device__ __forceinline__ short8 zfrag(uint2 p) {
    union { unsigned int u[4]; short8 s; } t;
    t.u[0] = p.x; t.u[1] = p.y; t.u[2] = 0u; t.u[3] = 0u;
    return t.s;
}
__device__ __forceinline__ f32x4 mfma16(uint2 a, uint2 b, f32x4 c) {
    return MFMA(zfrag(a), zfrag(b), c);
}
#endif

#define EXP2(x) exp2f(x)

// d_ws layout (elements of unsigned short):
//  [0 .. 196608)    wpk: QKV weights in MFMA-FRAGMENT order:
//                   frag f = ((m*8+h)*2+dt)*8+ks, elem = f*512 + lane*8 + j
//                   value = w_qkv[k=ks*32+(lane>>4)*8+j][n=m*256+h*32+dt*16+(lane&15)]
//  [196608..262144) wprojT [256][256]  (wprojT[n][k] = w_proj[k][n])
//  [262144 .. )     Ob bf16 [262144 tok (SPATIAL order)][256 ch]
__global__ void prep_w(const float* __restrict__ wqkv, const float* __restrict__ wproj,
                       unsigned short* __restrict__ wT) {
    int idx = blockIdx.x * 256 + threadIdx.x;   // 0..262143
    if (idx < 196608) {
        const int frag   = idx >> 9;        // 0..383
        const int within = idx & 511;
        const int lane = within >> 3, j = within & 7;
        const int ks = frag & 7;
        const int dt = (frag >> 3) & 1;
        const int hh = (frag >> 4) & 7;
        const int m  = frag >> 7;
        const int n = m * 256 + hh * 32 + dt * 16 + (lane & 15);
        const int k = ks * 32 + ((lane >> 4) << 3) + j;
        wT[idx] = f2bf1(wqkv[k * 768 + n]);
    } else {
        const int r = idx - 196608;
        const int n = r >> 8, k = r & 255;
        wT[idx] = f2bf1(wproj[(k << 8) + n]);
    }
}

// ============ Kernel A: per-window QKV + attention (column-streamed) ============
// Block = window (4 waves); each wave loops over heads {wid, wid+4}.
// Per head: K pass -> V pass -> stream 4 query columns (Q gemm, S, softmax, PV,
// immediate O store). Persistent regs: pkk 16 + pv2 16; peak total ~110.
__global__ __launch_bounds__(256, 2)
void attn_qkv(const float* __restrict__ x,
              const float* __restrict__ bqkv,
              const unsigned short* __restrict__ wpk,
              unsigned short* __restrict__ Ob)
{
    __shared__ unsigned short smem[64 * 256];   // 32 KiB: x only

    const int tid  = threadIdx.x;
    const int wid  = tid >> 6;
    const int lane = tid & 63;
    const int g    = lane >> 4;
    const int q16  = lane & 15;

    // XCD chunking: consecutive windows on the same XCD for weight/L2 locality
    const int bid  = blockIdx.x;
    const int widx = (bid & 7) * 512 + (bid >> 3);

    const int b  = widx >> 10;
    const int wh = (widx >> 5) & 31;
    const int ww = widx & 31;

    // ---- stage x window -> LDS bf16 (swizzled); ONCE per window ----
    {
        const int t  = tid >> 2;           // token 0..63
        const int c0 = (tid & 3) << 3;     // channel base
        const int hr = (wh << 3) + (t >> 3);
        const int wc = (ww << 3) + (t & 7);
        const float* rowp = x + (((size_t)b * 256 + hr) * 256 + wc) * 256;
        #pragma unroll
        for (int u = 0; u < 8; ++u) {
            const int c = c0 + (u << 5);
            const float4 f0 = *reinterpret_cast<const float4*>(rowp + c);
            const float4 f1 = *reinterpret_cast<const float4*>(rowp + c + 4);
            union { unsigned int u4[4]; short8 s; } pv;
            pv.u4[0] = pk2(f0.x, f0.y); pv.u4[1] = pk2(f0.z, f0.w);
            pv.u4[2] = pk2(f1.x, f1.y); pv.u4[3] = pk2(f1.z, f1.w);
            *reinterpret_cast<short8*>(&smem[XS(t, c)]) = pv.s;
        }
    }
    __syncthreads();   // the ONLY barrier in this kernel

    const f32x4 fz = {0.f, 0.f, 0.f, 0.f};
    const float SCL = 0.17677669529663687f * 1.4426950408889634f;  // scale*log2e
    const int loff = lane << 3;

    for (int p = 0; p < 2; ++p) {
        const int h = (p << 2) + wid;   // this wave's head for this iteration
        const unsigned short* wh0 = wpk + ((size_t)h << 13);

        // ===== pass K (m=1): k[tok=tt*16+q16][d=dt*16+g*4+{0..3}] = W_k·x^T =====
        uint2 pkk[2][4];
        {
            f32x4 acc[2][4];
            #pragma unroll
            for (int dt = 0; dt < 2; ++dt)
                #pragma unroll
                for (int tt = 0; tt < 4; ++tt) acc[dt][tt] = fz;
            const unsigned short* wb = wh0 + ((size_t)8 << 13);
            #pragma unroll
            for (int ks = 0; ks < 8; ++ks) {
                const int kc = ks << 5;
                short8 xf[4];
                #pragma unroll
                for (int tt = 0; tt < 4; ++tt)
                    xf[tt] = *reinterpret_cast<const short8*>(&smem[XS(tt * 16 + q16, kc + (g << 3))]);
                #pragma unroll
                for (int dt = 0; dt < 2; ++dt) {
                    const short8 wf = *reinterpret_cast<const short8*>(
                        wb + (((dt << 3) + ks) << 9) + loff);
                    #pragma unroll
                    for (int tt = 0; tt < 4; ++tt)
                        acc[dt][tt] = MFMA(wf, xf[tt], acc[dt][tt]);
                }
            }
            #pragma unroll
            for (int dt = 0; dt < 2; ++dt) {
                const float4 bb = *reinterpret_cast<const float4*>(
                    bqkv + 256 + h * 32 + dt * 16 + (g << 2));
                #pragma unroll
                for (int tt = 0; tt < 4; ++tt) {
                    const f32x4 a = acc[dt][tt];
                    pkk[dt][tt] = make_uint2(pk2(a[0] + bb.x, a[1] + bb.y),
                                             pk2(a[2] + bb.z, a[3] + bb.w));
                }
            }
        }

        // ===== pass V (m=2): v[tok=tt*16+g*4+{0..3}][d=dt*16+q16] = x·W_v =====
        uint2 pv2[2][4];
        {
            f32x4 acc[2][4];
            #pragma unroll
            for (int dt = 0; dt < 2; ++dt)
                #pragma unroll
                for (int tt = 0; tt < 4; ++tt) acc[dt][tt] = fz;
            const unsigned short* wb = wh0 + ((size_t)16 << 13);
            #pragma unroll
            for (int ks = 0; ks < 8; ++ks) {
                const int kc = ks << 5;
                short8 xf[4];
                #pragma unroll
                for (int tt = 0; tt < 4; ++tt)
                    xf[tt] = *reinterpret_cast<const short8*>(&smem[XS(tt * 16 + q16, kc + (g << 3))]);
                #pragma unroll
                for (int dt = 0; dt < 2; ++dt) {
                    const short8 wf = *reinterpret_cast<const short8*>(
                        wb + (((dt << 3) + ks) << 9) + loff);
                    #pragma unroll
                    for (int tt = 0; tt < 4; ++tt)
                        acc[dt][tt] = MFMA(xf[tt], wf, acc[dt][tt]);
                }
            }
            #pragma unroll
            for (int dt = 0; dt < 2; ++dt) {
                const float bv = bqkv[512 + h * 32 + dt * 16 + q16];
                #pragma unroll
                for (int tt = 0; tt < 4; ++tt) {
                    const f32x4 a = acc[dt][tt];
                    pv2[dt][tt] = make_uint2(pk2(a[0] + bv, a[1] + bv),
                                             pk2(a[2] + bv, a[3] + bv));
                }
            }
        }

        // ===== stream query columns =====
        const float4 bbq0 = *reinterpret_cast<const float4*>(bqkv + h * 32 + (g << 2));
        const float4 bbq1 = *reinterpret_cast<const float4*>(bqkv + h * 32 + 16 + (g << 2));
        #pragma unroll
        for (int qt = 0; qt < 4; ++qt) {
            // Q column GEMM: q[tok=qt*16+q16][d=dt*16+g*4+{0..3}]
            f32x4 accq[2] = {fz, fz};
            #pragma unroll
            for (int ks = 0; ks < 8; ++ks) {
                const int kc = ks << 5;
                const short8 xf = *reinterpret_cast<const short8*>(
                    &smem[XS(qt * 16 + q16, kc + (g << 3))]);
                #pragma unroll
                for (int dt = 0; dt < 2; ++dt) {
                    const short8 wf = *reinterpret_cast<const short8*>(
                        wh0 + (((dt << 3) + ks) << 9) + loff);
                    accq[dt] = MFMA(wf, xf, accq[dt]);
                }
            }
            uint2 pqc[2];
            pqc[0] = make_uint2(pk2((accq[0][0] + bbq0.x) * SCL, (accq[0][1] + bbq0.y) * SCL),
                                pk2((accq[0][2] + bbq0.z) * SCL, (accq[0][3] + bbq0.w) * SCL));
            pqc[1] = make_uint2(pk2((accq[1][0] + bbq1.x) * SCL, (accq[1][1] + bbq1.y) * SCL),
                                pk2((accq[1][2] + bbq1.z) * SCL, (accq[1][3] + bbq1.w) * SCL));

            // S column: S^T[key=kt*16+g*4+r][qtok=qt*16+q16]
            f32x4 st[4];
            #pragma unroll
            for (int kt = 0; kt < 4; ++kt) st[kt] = fz;
            #pragma unroll
            for (int dt = 0; dt < 2; ++dt)
                #pragma unroll
                for (int kt = 0; kt < 4; ++kt)
                    st[kt] = mfma16(pkk[dt][kt], pqc[dt], st[kt]);

            // softmax over keys (exp2, no max-sub), unnormalized
            uint2 ppkc[4];
            float sum = 0.f;
            #pragma unroll
            for (int kt = 0; kt < 4; ++kt) {
                const float e0 = EXP2(st[kt][0]), e1 = EXP2(st[kt][1]);
                const float e2 = EXP2(st[kt][2]), e3 = EXP2(st[kt][3]);
                sum += (e0 + e1) + (e2 + e3);
                ppkc[kt] = make_uint2(pk2(e0, e1), pk2(e2, e3));
            }
            sum += __shfl_xor(sum, 16);
            sum += __shfl_xor(sum, 32);
            const float iv = 1.f / sum;

            // PV column: O[tok=qt*16+q16][d=h*32+dt*16+g*4+r]
            f32x4 otc[2] = {fz, fz};
            #pragma unroll
            for (int kt = 0; kt < 4; ++kt)
                #pragma unroll
                for (int dt = 0; dt < 2; ++dt)
                    otc[dt] = mfma16(pv2[dt][kt], ppkc[kt], otc[dt]);

            // immediate O column store (spatial row order)
            const int tok = qt * 16 + q16;
            const size_t srow = (((size_t)(b << 8) + (wh << 3) + (tok >> 3)) << 8)
                                + (ww << 3) + (tok & 7);
            unsigned short* drow = Ob + (srow << 8) + h * 32 + (g << 2);
            #pragma unroll
            for (int dt = 0; dt < 2; ++dt) {
                const uint2 pv = make_uint2(pk2(otc[dt][0] * iv, otc[dt][1] * iv),
                                            pk2(otc[dt][2] * iv, otc[dt][3] * iv));
                *reinterpret_cast<uint2*>(drow + dt * 16) = pv;
            }
        }
    }
}

// ============ Kernel B: proj GEMM  out = O @ wproj + bias ============
__global__ __launch_bounds__(256, 2)
void proj_gemm(const unsigned short* __restrict__ Ob,
               const unsigned short* __restrict__ wprojT,
               const float* __restrict__ bproj,
               float* __restrict__ out)
{
    __shared__ unsigned short As[2][128 * 64];   // 16KB each
    __shared__ unsigned short Bs[2][128 * 64];

    const int tid  = threadIdx.x;
    const int wid  = tid >> 6;
    const int lane = tid & 63;
    const int g    = lane >> 4;
    const int q16  = lane & 15;
    const int wr   = wid >> 1, wc = wid & 1;

    // XCD-pairing swizzle: (mt, nt=0/1) pair shares the A-tile on one XCD
    const int bid = blockIdx.x;
    const int q   = bid >> 3;
    const int mt  = (bid & 7) * 256 + (q >> 1);
    const int nt  = q & 1;
    const size_t mrow0 = (size_t)mt << 7;
    const int nrow0 = nt << 7;

    const f32x4 fz = {0.f, 0.f, 0.f, 0.f};
    f32x4 acc[4][4];
    #pragma unroll
    for (int i = 0; i < 4; ++i)
        #pragma unroll
        for (int j = 0; j < 4; ++j) acc[i][j] = fz;

    int buf = 0;
    // prologue stage s=0
    #pragma unroll
    for (int i = 0; i < 4; ++i) {
        const int chunk = (i << 8) + tid;
        const int r = chunk >> 3, c = chunk & 7;
        const int cs = c ^ (r & 7);
        const uint4 va = *reinterpret_cast<const uint4*>(Ob + ((mrow0 + r) << 8) + (c << 3));
        *reinterpret_cast<uint4*>(&As[0][(r << 6) + (cs << 3)]) = va;
        const uint4 vb = *reinterpret_cast<const uint4*>(wprojT + ((size_t)(nrow0 + r) << 8) + (c << 3));
        *reinterpret_cast<uint4*>(&Bs[0][(r << 6) + (cs << 3)]) = vb;
    }
    __syncthreads();

    for (int s = 0; s < 4; ++s) {
        if (s < 3) {
            const int so = (s + 1) << 6;
            #pragma unroll
            for (int i = 0; i < 4; ++i) {
                const int chunk = (i << 8) + tid;
                const int r = chunk >> 3, c = chunk & 7;
                const int cs = c ^ (r & 7);
                const uint4 va = *reinterpret_cast<const uint4*>(Ob + ((mrow0 + r) << 8) + so + (c << 3));
                *reinterpret_cast<uint4*>(&As[buf ^ 1][(r << 6) + (cs << 3)]) = va;
                const uint4 vb = *reinterpret_cast<const uint4*>(wprojT + ((size_t)(nrow0 + r) << 8) + so + (c << 3));
                *reinterpret_cast<uint4*>(&Bs[buf ^ 1][(r << 6) + (cs << 3)]) = vb;
            }
        }
        #pragma unroll
        for (int kk = 0; kk < 2; ++kk) {
            short8 aF[4], bF[4];
            #pragma unroll
            for (int i = 0; i < 4; ++i) {
                const int rA = (wr << 6) + (i << 4) + q16;
                const int cA = ((kk << 2) + g) ^ (rA & 7);
                aF[i] = *reinterpret_cast<const short8*>(&As[buf][(rA << 6) + (cA << 3)]);
                const int rB = (wc << 6) + (i << 4) + q16;
                const int cB = ((kk << 2) + g) ^ (rB & 7);
                bF[i] = *reinterpret_cast<const short8*>(&Bs[buf][(rB << 6) + (cB << 3)]);
            }
            #pragma unroll
            for (int i = 0; i < 4; ++i)
                #pragma unroll
                for (int j = 0; j < 4; ++j)
                    acc[i][j] = MFMA(aF[i], bF[j], acc[i][j]);
        }
        __syncthreads();
        buf ^= 1;
    }

    // epilogue: rows are spatial order -> direct coalesced store
    #pragma unroll
    for (int j = 0; j < 4; ++j) {
        const int coln = nrow0 + (wc << 6) + (j << 4) + q16;
        const float bp = bproj[coln];
        #pragma unroll
        for (int i = 0; i < 4; ++i) {
            const size_t row = mrow0 + (wr << 6) + (i << 4) + (g << 2);
            #pragma unroll
            for (int rr = 0; rr < 4; ++rr)
                out[((row + rr) << 8) + coln] = acc[i][j][rr] + bp;
        }
    }
}

extern "C" void kernel_launch(void* const* d_in, const int* in_sizes, int n_in,
                              void* d_out, int out_size, void* d_ws, size_t ws_size,
                              hipStream_t stream) {
    const float* x     = (const float*)d_in[0];
    const float* wqkv  = (const float*)d_in[1];
    const float* bqkv  = (const float*)d_in[2];
    const float* wproj = (const float*)d_in[3];
    const float* bproj = (const float*)d_in[4];
    float* out = (float*)d_out;
    unsigned short* wT = (unsigned short*)d_ws;

    prep_w<<<1024, 256, 0, stream>>>(wqkv, wproj, wT);
    unsigned short* Ob = wT + 262144;   // byte offset 524288
    attn_qkv<<<4096, 256, 0, stream>>>(x, bqkv, wT, Ob);
    proj_gemm<<<4096, 256, 0, stream>>>(Ob, wT + 196608, bproj, out);
}

// Round 12
// 392.502 us; speedup vs baseline: 1.2015x; 1.2015x over previous
//
#include <hip/hip_runtime.h>
#include <hip/hip_bf16.h>

typedef __attribute__((ext_vector_type(8))) short short8;
typedef __attribute__((ext_vector_type(4))) short short4v;
typedef __attribute__((ext_vector_type(4))) float f32x4;

#define MFMA(a, b, c) __builtin_amdgcn_mfma_f32_16x16x32_bf16(a, b, c, 0, 0, 0)
// XOR-swizzled [64][256] bf16 LDS index (8-elem granule), x region only
#define XS(t, c) (((t) << 8) + ((c) ^ (((t) & 7) << 3)))

__device__ __forceinline__ unsigned int pk2(float lo, float hi) {
    union { __hip_bfloat162 h2; unsigned int u; } cv;
    cv.h2 = __float22bfloat162_rn(make_float2(lo, hi));
    return cv.u;
}

__device__ __forceinline__ unsigned short f2bf1(float f) {
    unsigned int u = __float_as_uint(f);
    u += 0x7FFFu + ((u >> 16) & 1u);
    return (unsigned short)(u >> 16);
}

__device__ __forceinline__ short4v u2s4(uint2 p) {
    union { uint2 u; short4v s; } t; t.u = p; return t.s;
}

#if __has_builtin(__builtin_amdgcn_mfma_f32_16x16x16bf16_1k)
__device__ __forceinline__ f32x4 mfma16(uint2 a, uint2 b, f32x4 c) {
    return __builtin_amdgcn_mfma_f32_16x16x16bf16_1k(u2s4(a), u2s4(b), c, 0, 0, 0);
}
#else
__device__ __forceinline__ short8 zfrag(uint2 p) {
    union { unsigned int u[4]; short8 s; } t;
    t.u[0] = p.x; t.u[1] = p.y; t.u[2] = 0u; t.u[3] = 0u;
    return t.s;
}
__device__ __forceinline__ f32x4 mfma16(uint2 a, uint2 b, f32x4 c) {
    return MFMA(zfrag(a), zfrag(b), c);
}
#endif

#define EXP2(x) exp2f(x)

// d_ws layout (elements of unsigned short):
//  [0 .. 196608)    wpk: QKV weights in MFMA-FRAGMENT order:
//                   frag f = ((m*8+h)*2+dt)*8+ks, elem = f*512 + lane*8 + j
//                   value = w_qkv[k=ks*32+(lane>>4)*8+j][n=m*256+h*32+dt*16+(lane&15)]
//  [196608..262144) wprojT [256][256]  (wprojT[n][k] = w_proj[k][n])
//  [262144 .. )     Ob bf16 [262144 tok (SPATIAL order)][256 ch]
__global__ void prep_w(const float* __restrict__ wqkv, const float* __restrict__ wproj,
                       unsigned short* __restrict__ wT) {
    int idx = blockIdx.x * 256 + threadIdx.x;   // 0..262143
    if (idx < 196608) {
        const int frag   = idx >> 9;        // 0..383
        const int within = idx & 511;
        const int lane = within >> 3, j = within & 7;
        const int ks = frag & 7;
        const int dt = (frag >> 3) & 1;
        const int hh = (frag >> 4) & 7;
        const int m  = frag >> 7;
        const int n = m * 256 + hh * 32 + dt * 16 + (lane & 15);
        const int k = ks * 32 + ((lane >> 4) << 3) + j;
        wT[idx] = f2bf1(wqkv[k * 768 + n]);
    } else {
        const int r = idx - 196608;
        const int n = r >> 8, k = r & 255;
        wT[idx] = f2bf1(wproj[(k << 8) + n]);
    }
}

// ============ Kernel A: per-window QKV + attention, LDS-resident K/V ============
// 512 thr = 8 waves; 2 rounds x 4 heads; wave = (head = r*4 + (w>>1), half = w&1).
// Phase 1: q for 2 query-cols (regs) + k,v for its token-half -> LDS frags.
// Phase 2: per query-col: S (k frags from LDS), softmax, PV (v frags), store O.
// Peak VGPR ~55 -> launch_bounds(512,4) cap 64, NO spill; LDS 64KB -> 2 blocks/CU
// -> 16 waves/CU (2x R10's occupancy).
__global__ __launch_bounds__(512, 4)
void attn_qkv(const float* __restrict__ x,
              const float* __restrict__ bqkv,
              const unsigned short* __restrict__ wpk,
              unsigned short* __restrict__ Ob)
{
    __shared__ unsigned short smem[32768];   // 64KB: x[16384] | K[8192] | V[8192] elems

    const int tid  = threadIdx.x;
    const int w    = tid >> 6;
    const int lane = tid & 63;
    const int g    = lane >> 4;
    const int q16  = lane & 15;
    const int hh   = w >> 1;          // local head 0..3
    const int hf   = w & 1;           // half index (token-half for k/v, col-half for q)

    // XCD chunking: consecutive windows on the same XCD
    const int bid  = blockIdx.x;
    const int widx = (bid & 7) * 512 + (bid >> 3);
    const int b  = widx >> 10;
    const int wh = (widx >> 5) & 31;
    const int ww = widx & 31;

    // ---- stage x window -> LDS bf16 (swizzled), once per window ----
    {
        const int t  = tid >> 3;              // token 0..63
        const int c0 = (tid & 7) << 3;        // channel base
        const int hr = (wh << 3) + (t >> 3);
        const int wc = (ww << 3) + (t & 7);
        const float* rowp = x + (((size_t)b * 256 + hr) * 256 + wc) * 256;
        #pragma unroll
        for (int u = 0; u < 4; ++u) {
            const int c = c0 + (u << 6);
            const float4 f0 = *reinterpret_cast<const float4*>(rowp + c);
            const float4 f1 = *reinterpret_cast<const float4*>(rowp + c + 4);
            union { unsigned int u4[4]; short8 s; } pv;
            pv.u4[0] = pk2(f0.x, f0.y); pv.u4[1] = pk2(f0.z, f0.w);
            pv.u4[2] = pk2(f1.x, f1.y); pv.u4[3] = pk2(f1.z, f1.w);
            *reinterpret_cast<short8*>(&smem[XS(t, c)]) = pv.s;
        }
    }
    __syncthreads();

    const f32x4 fz = {0.f, 0.f, 0.f, 0.f};
    const float SCL = 0.17677669529663687f * 1.4426950408889634f;  // scale*log2e
    const int loff = lane << 3;
    // K frag slot (elements): 16384 + ((hh*2+dt)*4 + kt)*256 + lane*4 ; V: +8192
    const int kvl = (lane << 2);

    #pragma unroll 1
    for (int r = 0; r < 2; ++r) {
        const int h = (r << 2) + hh;
        const unsigned short* wh0 = wpk + ((size_t)h << 13);

        // ===== phase 1a: q for columns qt = hf*2 + {0,1} (kept in regs) =====
        uint2 pq[2][2];   // [cc][dt]
        {
            f32x4 acc[2][2];
            #pragma unroll
            for (int cc = 0; cc < 2; ++cc)
                #pragma unroll
                for (int dt = 0; dt < 2; ++dt) acc[cc][dt] = fz;
            #pragma unroll
            for (int ks = 0; ks < 8; ++ks) {
                const int kc = ks << 5;
                short8 xf[2];
                #pragma unroll
                for (int cc = 0; cc < 2; ++cc)
                    xf[cc] = *reinterpret_cast<const short8*>(
                        &smem[XS(((hf << 1) + cc) * 16 + q16, kc + (g << 3))]);
                #pragma unroll
                for (int dt = 0; dt < 2; ++dt) {
                    const short8 wf = *reinterpret_cast<const short8*>(
                        wh0 + (((dt << 3) + ks) << 9) + loff);
                    #pragma unroll
                    for (int cc = 0; cc < 2; ++cc)
                        acc[cc][dt] = MFMA(wf, xf[cc], acc[cc][dt]);
                }
            }
            #pragma unroll
            for (int dt = 0; dt < 2; ++dt) {
                const float4 bb = *reinterpret_cast<const float4*>(
                    bqkv + h * 32 + dt * 16 + (g << 2));
                #pragma unroll
                for (int cc = 0; cc < 2; ++cc) {
                    const f32x4 a = acc[cc][dt];
                    pq[cc][dt] = make_uint2(pk2((a[0] + bb.x) * SCL, (a[1] + bb.y) * SCL),
                                            pk2((a[2] + bb.z) * SCL, (a[3] + bb.w) * SCL));
                }
            }
        }

        // ===== phase 1b: k for token-tiles kt = hf*2 + {0,1} -> LDS frags =====
        {
            f32x4 acc[2][2];   // [tt][dt]
            #pragma unroll
            for (int tt = 0; tt < 2; ++tt)
                #pragma unroll
                for (int dt = 0; dt < 2; ++dt) acc[tt][dt] = fz;
            const unsigned short* wb = wh0 + ((size_t)8 << 13);   // m=1
            #pragma unroll
            for (int ks = 0; ks < 8; ++ks) {
                const int kc = ks << 5;
                short8 xf[2];
                #pragma unroll
                for (int tt = 0; tt < 2; ++tt)
                    xf[tt] = *reinterpret_cast<const short8*>(
                        &smem[XS(((hf << 1) + tt) * 16 + q16, kc + (g << 3))]);
                #pragma unroll
                for (int dt = 0; dt < 2; ++dt) {
                    const short8 wf = *reinterpret_cast<const short8*>(
                        wb + (((dt << 3) + ks) << 9) + loff);
                    #pragma unroll
                    for (int tt = 0; tt < 2; ++tt)
                        acc[tt][dt] = MFMA(wf, xf[tt], acc[tt][dt]);
                }
            }
            #pragma unroll
            for (int dt = 0; dt < 2; ++dt) {
                const float4 bb = *reinterpret_cast<const float4*>(
                    bqkv + 256 + h * 32 + dt * 16 + (g << 2));
                #pragma unroll
                for (int tt = 0; tt < 2; ++tt) {
                    const f32x4 a = acc[tt][dt];
                    const uint2 pv = make_uint2(pk2(a[0] + bb.x, a[1] + bb.y),
                                                pk2(a[2] + bb.z, a[3] + bb.w));
                    const int kt = (hf << 1) + tt;
                    *reinterpret_cast<uint2*>(
                        &smem[16384 + ((((hh << 1) + dt) << 2) + kt) * 256 + kvl]) = pv;
                }
            }
        }

        // ===== phase 1c: v for token-tiles kt = hf*2 + {0,1} -> LDS frags =====
        {
            f32x4 acc[2][2];   // [tt][dt]
            #pragma unroll
            for (int tt = 0; tt < 2; ++tt)
                #pragma unroll
                for (int dt = 0; dt < 2; ++dt) acc[tt][dt] = fz;
            const unsigned short* wb = wh0 + ((size_t)16 << 13);   // m=2
            #pragma unroll
            for (int ks = 0; ks < 8; ++ks) {
                const int kc = ks << 5;
                short8 xf[2];
                #pragma unroll
                for (int tt = 0; tt < 2; ++tt)
                    xf[tt] = *reinterpret_cast<const short8*>(
                        &smem[XS(((hf << 1) + tt) * 16 + q16, kc + (g << 3))]);
                #pragma unroll
                for (int dt = 0; dt < 2; ++dt) {
                    const short8 wf = *reinterpret_cast<const short8*>(
                        wb + (((dt << 3) + ks) << 9) + loff);
                    #pragma unroll
                    for (int tt = 0; tt < 2; ++tt)
                        acc[tt][dt] = MFMA(xf[tt], wf, acc[tt][dt]);
                }
            }
            #pragma unroll
            for (int dt = 0; dt < 2; ++dt) {
                const float bv = bqkv[512 + h * 32 + dt * 16 + q16];
                #pragma unroll
                for (int tt = 0; tt < 2; ++tt) {
                    const f32x4 a = acc[tt][dt];
                    const uint2 pv = make_uint2(pk2(a[0] + bv, a[1] + bv),
                                                pk2(a[2] + bv, a[3] + bv));
                    const int kt = (hf << 1) + tt;
                    *reinterpret_cast<uint2*>(
                        &smem[24576 + ((((hh << 1) + dt) << 2) + kt) * 256 + kvl]) = pv;
                }
            }
        }
        __syncthreads();   // k,v frags complete for all heads

        // ===== phase 2: stream this wave's 2 query columns =====
        #pragma unroll
        for (int cc = 0; cc < 2; ++cc) {
            const int qt = (hf << 1) + cc;
            // S column: S^T[key=kt*16+g*4+r][qtok=qt*16+q16]
            f32x4 st[4];
            #pragma unroll
            for (int kt = 0; kt < 4; ++kt) st[kt] = fz;
            #pragma unroll
            for (int dt = 0; dt < 2; ++dt) {
                const uint2 qf = pq[cc][dt];
                #pragma unroll
                for (int kt = 0; kt < 4; ++kt) {
                    const uint2 kf = *reinterpret_cast<const uint2*>(
                        &smem[16384 + ((((hh << 1) + dt) << 2) + kt) * 256 + kvl]);
                    st[kt] = mfma16(kf, qf, st[kt]);
                }
            }
            // softmax over keys (exp2, no max-sub), unnormalized
            uint2 ppkc[4];
            float sum = 0.f;
            #pragma unroll
            for (int kt = 0; kt < 4; ++kt) {
                const float e0 = EXP2(st[kt][0]), e1 = EXP2(st[kt][1]);
                const float e2 = EXP2(st[kt][2]), e3 = EXP2(st[kt][3]);
                sum += (e0 + e1) + (e2 + e3);
                ppkc[kt] = make_uint2(pk2(e0, e1), pk2(e2, e3));
            }
            sum += __shfl_xor(sum, 16);
            sum += __shfl_xor(sum, 32);
            const float iv = 1.f / sum;

            // PV column: O[tok=qt*16+q16][d=h*32+dt*16+g*4+r]
            f32x4 otc[2] = {fz, fz};
            #pragma unroll
            for (int kt = 0; kt < 4; ++kt) {
                const uint2 pf = ppkc[kt];
                #pragma unroll
                for (int dt = 0; dt < 2; ++dt) {
                    const uint2 vf = *reinterpret_cast<const uint2*>(
                        &smem[24576 + ((((hh << 1) + dt) << 2) + kt) * 256 + kvl]);
                    otc[dt] = mfma16(vf, pf, otc[dt]);
                }
            }
            // O column store (spatial row order)
            const int tok = qt * 16 + q16;
            const size_t srow = (((size_t)(b << 8) + (wh << 3) + (tok >> 3)) << 8)
                                + (ww << 3) + (tok & 7);
            unsigned short* drow = Ob + (srow << 8) + h * 32 + (g << 2);
            #pragma unroll
            for (int dt = 0; dt < 2; ++dt) {
                const uint2 pv = make_uint2(pk2(otc[dt][0] * iv, otc[dt][1] * iv),
                                            pk2(otc[dt][2] * iv, otc[dt][3] * iv));
                *reinterpret_cast<uint2*>(drow + dt * 16) = pv;
            }
        }
        __syncthreads();   // phase-2 reads done before next round overwrites K/V
    }
}

// ============ Kernel B: proj GEMM  out = O @ wproj + bias ============
__global__ __launch_bounds__(256, 2)
void proj_gemm(const unsigned short* __restrict__ Ob,
               const unsigned short* __restrict__ wprojT,
               const float* __restrict__ bproj,
               float* __restrict__ out)
{
    __shared__ unsigned short As[2][128 * 64];   // 16KB each
    __shared__ unsigned short Bs[2][128 * 64];

    const int tid  = threadIdx.x;
    const int wid  = tid >> 6;
    const int lane = tid & 63;
    const int g    = lane >> 4;
    const int q16  = lane & 15;
    const int wr   = wid >> 1, wc = wid & 1;

    // XCD-pairing swizzle: (mt, nt=0/1) pair shares the A-tile on one XCD
    const int bid = blockIdx.x;
    const int q   = bid >> 3;
    const int mt  = (bid & 7) * 256 + (q >> 1);
    const int nt  = q & 1;
    const size_t mrow0 = (size_t)mt << 7;
    const int nrow0 = nt << 7;

    const f32x4 fz = {0.f, 0.f, 0.f, 0.f};
    f32x4 acc[4][4];
    #pragma unroll
    for (int i = 0; i < 4; ++i)
        #pragma unroll
        for (int j = 0; j < 4; ++j) acc[i][j] = fz;

    int buf = 0;
    #pragma unroll
    for (int i = 0; i < 4; ++i) {
        const int chunk = (i << 8) + tid;
        const int r = chunk >> 3, c = chunk & 7;
        const int cs = c ^ (r & 7);
        const uint4 va = *reinterpret_cast<const uint4*>(Ob + ((mrow0 + r) << 8) + (c << 3));
        *reinterpret_cast<uint4*>(&As[0][(r << 6) + (cs << 3)]) = va;
        const uint4 vb = *reinterpret_cast<const uint4*>(wprojT + ((size_t)(nrow0 + r) << 8) + (c << 3));
        *reinterpret_cast<uint4*>(&Bs[0][(r << 6) + (cs << 3)]) = vb;
    }
    __syncthreads();

    for (int s = 0; s < 4; ++s) {
        if (s < 3) {
            const int so = (s + 1) << 6;
            #pragma unroll
            for (int i = 0; i < 4; ++i) {
                const int chunk = (i << 8) + tid;
                const int r = chunk >> 3, c = chunk & 7;
                const int cs = c ^ (r & 7);
                const uint4 va = *reinterpret_cast<const uint4*>(Ob + ((mrow0 + r) << 8) + so + (c << 3));
                *reinterpret_cast<uint4*>(&As[buf ^ 1][(r << 6) + (cs << 3)]) = va;
                const uint4 vb = *reinterpret_cast<const uint4*>(wprojT + ((size_t)(nrow0 + r) << 8) + so + (c << 3));
                *reinterpret_cast<uint4*>(&Bs[buf ^ 1][(r << 6) + (cs << 3)]) = vb;
            }
        }
        #pragma unroll
        for (int kk = 0; kk < 2; ++kk) {
            short8 aF[4], bF[4];
            #pragma unroll
            for (int i = 0; i < 4; ++i) {
                const int rA = (wr << 6) + (i << 4) + q16;
                const int cA = ((kk << 2) + g) ^ (rA & 7);
                aF[i] = *reinterpret_cast<const short8*>(&As[buf][(rA << 6) + (cA << 3)]);
                const int rB = (wc << 6) + (i << 4) + q16;
                const int cB = ((kk << 2) + g) ^ (rB & 7);
                bF[i] = *reinterpret_cast<const short8*>(&Bs[buf][(rB << 6) + (cB << 3)]);
            }
            #pragma unroll
            for (int i = 0; i < 4; ++i)
                #pragma unroll
                for (int j = 0; j < 4; ++j)
                    acc[i][j] = MFMA(aF[i], bF[j], acc[i][j]);
        }
        __syncthreads();
        buf ^= 1;
    }

    // epilogue: rows are spatial order -> direct coalesced store
    #pragma unroll
    for (int j = 0; j < 4; ++j) {
        const int coln = nrow0 + (wc << 6) + (j << 4) + q16;
        const float bp = bproj[coln];
        #pragma unroll
        for (int i = 0; i < 4; ++i) {
            const size_t row = mrow0 + (wr << 6) + (i << 4) + (g << 2);
            #pragma unroll
            for (int rr = 0; rr < 4; ++rr)
                out[((row + rr) << 8) + coln] = acc[i][j][rr] + bp;
        }
    }
}

extern "C" void kernel_launch(void* const* d_in, const int* in_sizes, int n_in,
                              void* d_out, int out_size, void* d_ws, size_t ws_size,
                              hipStream_t stream) {
    const float* x     = (const float*)d_in[0];
    const float* wqkv  = (const float*)d_in[1];
    const float* bqkv  = (const float*)d_in[2];
    const float* wproj = (const float*)d_in[3];
    const float* bproj = (const float*)d_in[4];
    float* out = (float*)d_out;
    unsigned short* wT = (unsigned short*)d_ws;

    prep_w<<<1024, 256, 0, stream>>>(wqkv, wproj, wT);
    unsigned short* Ob = wT + 262144;   // byte offset 524288
    attn_qkv<<<4096, 512, 0, stream>>>(x, bqkv, wT, Ob);
    proj_gemm<<<4096, 256, 0, stream>>>(Ob, wT + 196608, bproj, out);
}

// Round 13
// 309.622 us; speedup vs baseline: 1.5231x; 1.2677x over previous
//
#include <hip/hip_runtime.h>
#include <hip/hip_bf16.h>

typedef __attribute__((ext_vector_type(8))) short short8;
typedef __attribute__((ext_vector_type(4))) short short4v;
typedef __attribute__((ext_vector_type(4))) float f32x4;

#define MFMA(a, b, c) __builtin_amdgcn_mfma_f32_16x16x32_bf16(a, b, c, 0, 0, 0)
// XOR-swizzled [64][256] bf16 LDS index (8-elem granule)
#define XS(t, c) (((t) << 8) + ((c) ^ (((t) & 7) << 3)))

__device__ __forceinline__ unsigned int pk2(float lo, float hi) {
    union { __hip_bfloat162 h2; unsigned int u; } cv;
    cv.h2 = __float22bfloat162_rn(make_float2(lo, hi));
    return cv.u;
}

__device__ __forceinline__ unsigned short f2bf1(float f) {
    unsigned int u = __float_as_uint(f);
    u += 0x7FFFu + ((u >> 16) & 1u);
    return (unsigned short)(u >> 16);
}

__device__ __forceinline__ short4v u2s4(uint2 p) {
    union { uint2 u; short4v s; } t; t.u = p; return t.s;
}

#if __has_builtin(__builtin_amdgcn_mfma_f32_16x16x16bf16_1k)
__device__ __forceinline__ f32x4 mfma16(uint2 a, uint2 b, f32x4 c) {
    return __builtin_amdgcn_mfma_f32_16x16x16bf16_1k(u2s4(a), u2s4(b), c, 0, 0, 0);
}
#else
__device__ __forceinline__ short8 zfrag(uint2 p) {
    union { unsigned int u[4]; short8 s; } t;
    t.u[0] = p.x; t.u[1] = p.y; t.u[2] = 0u; t.u[3] = 0u;
    return t.s;
}
__device__ __forceinline__ f32x4 mfma16(uint2 a, uint2 b, f32x4 c) {
    return MFMA(zfrag(a), zfrag(b), c);
}
#endif

#define EXP2(x) exp2f(x)

// d_ws layout (elements of unsigned short):
//  [0 .. 196608)    wpk: QKV weights in MFMA-FRAGMENT order:
//                   frag f = ((m*8+h)*2+dt)*8+ks, elem = f*512 + lane*8 + j
//                   value = w_qkv[k=ks*32+(lane>>4)*8+j][n=m*256+h*32+dt*16+(lane&15)]
//  [196608..262144) wprojT [256][256]  (wprojT[n][k] = w_proj[k][n])
//  [262144 .. )     Ob bf16 [262144 tok (SPATIAL order)][256 ch]
__global__ void prep_w(const float* __restrict__ wqkv, const float* __restrict__ wproj,
                       unsigned short* __restrict__ wT) {
    int idx = blockIdx.x * 256 + threadIdx.x;   // 0..262143
    if (idx < 196608) {
        const int frag   = idx >> 9;        // 0..383
        const int within = idx & 511;
        const int lane = within >> 3, j = within & 7;
        const int ks = frag & 7;
        const int dt = (frag >> 3) & 1;
        const int hh = (frag >> 4) & 7;
        const int m  = frag >> 7;
        const int n = m * 256 + hh * 32 + dt * 16 + (lane & 15);
        const int k = ks * 32 + ((lane >> 4) << 3) + j;
        wT[idx] = f2bf1(wqkv[k * 768 + n]);
    } else {
        const int r = idx - 196608;
        const int n = r >> 8, k = r & 255;
        wT[idx] = f2bf1(wproj[(k << 8) + n]);
    }
}

// ============ Kernel A: per (window, head-quad) QKV + attention ============
// Single-xf-pass QKV: per half (2 token-tiles), one sweep over ks reads xf ONCE
// and feeds q,k,v x 2dt weight fragments (12 MFMA / 2 LDS reads). LDS reads
// per wave: 32 (vs 96 in 3-pass). Peak live ~106 regs < 128 cap (bounds(256,2)).
__global__ __launch_bounds__(256, 2)
void attn_qkv(const float* __restrict__ x,
              const float* __restrict__ bqkv,
              const unsigned short* __restrict__ wpk,
              unsigned short* __restrict__ Ob)
{
    __shared__ unsigned short smem[64 * 256];   // 32 KiB: x only

    const int tid  = threadIdx.x;
    const int wid  = tid >> 6;
    const int lane = tid & 63;
    const int g    = lane >> 4;
    const int q16  = lane & 15;

    // XCD-pairing swizzle: two head-quad blocks of a window on the same XCD.
    const int bid  = blockIdx.x;
    const int xcd  = bid & 7;
    const int q    = bid >> 3;
    const int widx = xcd * 512 + (q >> 1);
    const int hq   = (q & 1) << 2;     // head-quad base (0 or 4)
    const int h    = hq + wid;         // this wave's head

    const int b  = widx >> 10;
    const int wh = (widx >> 5) & 31;
    const int ww = widx & 31;

    // ---- stage x window -> LDS bf16 (swizzled) ----
    {
        const int t  = tid >> 2;           // token 0..63
        const int c0 = (tid & 3) << 3;     // channel base
        const int hr = (wh << 3) + (t >> 3);
        const int wc = (ww << 3) + (t & 7);
        const float* rowp = x + (((size_t)b * 256 + hr) * 256 + wc) * 256;
        #pragma unroll
        for (int u = 0; u < 8; ++u) {
            const int c = c0 + (u << 5);
            const float4 f0 = *reinterpret_cast<const float4*>(rowp + c);
            const float4 f1 = *reinterpret_cast<const float4*>(rowp + c + 4);
            union { unsigned int u4[4]; short8 s; } pv;
            pv.u4[0] = pk2(f0.x, f0.y); pv.u4[1] = pk2(f0.z, f0.w);
            pv.u4[2] = pk2(f1.x, f1.y); pv.u4[3] = pk2(f1.z, f1.w);
            *reinterpret_cast<short8*>(&smem[XS(t, c)]) = pv.s;
        }
    }
    __syncthreads();   // the ONLY barrier in this kernel

    const f32x4 fz = {0.f, 0.f, 0.f, 0.f};
    const float SCL = 0.17677669529663687f * 1.4426950408889634f;  // scale*log2e
    const unsigned short* wh0 = wpk + ((size_t)h << 13);   // head base; m stride 8<<13
    const int loff = lane << 3;

    // ===== merged QKV, single xf pass per half =====
    // pq/pkk: {q,k}[tok=tt*16+q16][d=dt*16+g*4+{0..3}]   (D = W·x^T), q pre-scaled
    // pv2   :  v[tok=tt*16+g*4+{0..3}][d=dt*16+q16]      (D = x·W)
    uint2 pq[2][4], pkk[2][4], pv2[2][4];
    #pragma unroll
    for (int half = 0; half < 2; ++half) {
        f32x4 acc[3][2][2];
        #pragma unroll
        for (int m = 0; m < 3; ++m)
            #pragma unroll
            for (int dt = 0; dt < 2; ++dt)
                #pragma unroll
                for (int t2 = 0; t2 < 2; ++t2) acc[m][dt][t2] = fz;

        #pragma unroll
        for (int ks = 0; ks < 8; ++ks) {
            const int kc = ks << 5;
            short8 xf[2];
            #pragma unroll
            for (int t2 = 0; t2 < 2; ++t2)
                xf[t2] = *reinterpret_cast<const short8*>(
                    &smem[XS(((half << 1) + t2) * 16 + q16, kc + (g << 3))]);
            #pragma unroll
            for (int m = 0; m < 3; ++m) {
                #pragma unroll
                for (int dt = 0; dt < 2; ++dt) {
                    const short8 wf = *reinterpret_cast<const short8*>(
                        wh0 + (((size_t)m << 16) | (((dt << 3) + ks) << 9)) + loff);
                    #pragma unroll
                    for (int t2 = 0; t2 < 2; ++t2)
                        acc[m][dt][t2] = (m < 2) ? MFMA(wf, xf[t2], acc[m][dt][t2])
                                                 : MFMA(xf[t2], wf, acc[m][dt][t2]);
                }
            }
        }
        // pack with bias (+SCL for q)
        #pragma unroll
        for (int dt = 0; dt < 2; ++dt) {
            const float4 bbq = *reinterpret_cast<const float4*>(bqkv + h * 32 + dt * 16 + (g << 2));
            const float4 bbk = *reinterpret_cast<const float4*>(bqkv + 256 + h * 32 + dt * 16 + (g << 2));
            const float bv = bqkv[512 + h * 32 + dt * 16 + q16];
            #pragma unroll
            for (int t2 = 0; t2 < 2; ++t2) {
                const int tt = (half << 1) + t2;
                const f32x4 aq = acc[0][dt][t2];
                pq[dt][tt]  = make_uint2(pk2((aq[0] + bbq.x) * SCL, (aq[1] + bbq.y) * SCL),
                                         pk2((aq[2] + bbq.z) * SCL, (aq[3] + bbq.w) * SCL));
                const f32x4 ak = acc[1][dt][t2];
                pkk[dt][tt] = make_uint2(pk2(ak[0] + bbk.x, ak[1] + bbk.y),
                                         pk2(ak[2] + bbk.z, ak[3] + bbk.w));
                const f32x4 av = acc[2][dt][t2];
                pv2[dt][tt] = make_uint2(pk2(av[0] + bv, av[1] + bv),
                                         pk2(av[2] + bv, av[3] + bv));
            }
        }
    }

    // ===== S^T = K·Q^T (K=16), exp2 (no max-sub), unnormalized P^T =====
    uint2 ppk[4][4];   // [kt][qt]: P^T[key=kt*16+g*4+{0..3}][qtok=qt*16+q16]
    float inv4[4];
    #pragma unroll
    for (int qt = 0; qt < 4; ++qt) {
        f32x4 st[4];
        #pragma unroll
        for (int kt = 0; kt < 4; ++kt) st[kt] = fz;
        #pragma unroll
        for (int dt = 0; dt < 2; ++dt)
            #pragma unroll
            for (int kt = 0; kt < 4; ++kt)
                st[kt] = mfma16(pkk[dt][kt], pq[dt][qt], st[kt]);
        float sum = 0.f;
        #pragma unroll
        for (int kt = 0; kt < 4; ++kt) {
            const float e0 = EXP2(st[kt][0]), e1 = EXP2(st[kt][1]);
            const float e2 = EXP2(st[kt][2]), e3 = EXP2(st[kt][3]);
            sum += (e0 + e1) + (e2 + e3);
            ppk[kt][qt] = make_uint2(pk2(e0, e1), pk2(e2, e3));
        }
        sum += __shfl_xor(sum, 16);
        sum += __shfl_xor(sum, 32);
        inv4[qt] = 1.f / sum;
    }

    // ===== O^T = V^T·P^T (K=16) =====
    f32x4 ot[2][4];    // lane: O[tok=tt*16+q16][d=h*32+dt*16+g*4+r]
    #pragma unroll
    for (int dt = 0; dt < 2; ++dt)
        #pragma unroll
        for (int tt = 0; tt < 4; ++tt) ot[dt][tt] = fz;
    #pragma unroll
    for (int kt = 0; kt < 4; ++kt)
        #pragma unroll
        for (int tt = 0; tt < 4; ++tt)
            #pragma unroll
            for (int dt = 0; dt < 2; ++dt)
                ot[dt][tt] = mfma16(pv2[dt][kt], ppk[kt][tt], ot[dt][tt]);

    // ===== direct global write of O (spatial row order) =====
    #pragma unroll
    for (int tt = 0; tt < 4; ++tt) {
        const float iv = inv4[tt];
        const int tok = tt * 16 + q16;
        const size_t srow = (((size_t)(b << 8) + (wh << 3) + (tok >> 3)) << 8)
                            + (ww << 3) + (tok & 7);
        unsigned short* drow = Ob + (srow << 8) + h * 32 + (g << 2);
        #pragma unroll
        for (int dt = 0; dt < 2; ++dt) {
            const uint2 pv = make_uint2(pk2(ot[dt][tt][0] * iv, ot[dt][tt][1] * iv),
                                        pk2(ot[dt][tt][2] * iv, ot[dt][tt][3] * iv));
            *reinterpret_cast<uint2*>(drow + dt * 16) = pv;
        }
    }
}

// ============ Kernel B: proj GEMM  out = O @ wproj + bias ============
__global__ __launch_bounds__(256, 2)
void proj_gemm(const unsigned short* __restrict__ Ob,
               const unsigned short* __restrict__ wprojT,
               const float* __restrict__ bproj,
               float* __restrict__ out)
{
    __shared__ unsigned short As[2][128 * 64];   // 16KB each
    __shared__ unsigned short Bs[2][128 * 64];

    const int tid  = threadIdx.x;
    const int wid  = tid >> 6;
    const int lane = tid & 63;
    const int g    = lane >> 4;
    const int q16  = lane & 15;
    const int wr   = wid >> 1, wc = wid & 1;

    // XCD-pairing swizzle: (mt, nt=0/1) pair shares the A-tile on one XCD
    const int bid = blockIdx.x;
    const int q   = bid >> 3;
    const int mt  = (bid & 7) * 256 + (q >> 1);
    const int nt  = q & 1;
    const size_t mrow0 = (size_t)mt << 7;
    const int nrow0 = nt << 7;

    const f32x4 fz = {0.f, 0.f, 0.f, 0.f};
    f32x4 acc[4][4];
    #pragma unroll
    for (int i = 0; i < 4; ++i)
        #pragma unroll
        for (int j = 0; j < 4; ++j) acc[i][j] = fz;

    int buf = 0;
    #pragma unroll
    for (int i = 0; i < 4; ++i) {
        const int chunk = (i << 8) + tid;
        const int r = chunk >> 3, c = chunk & 7;
        const int cs = c ^ (r & 7);
        const uint4 va = *reinterpret_cast<const uint4*>(Ob + ((mrow0 + r) << 8) + (c << 3));
        *reinterpret_cast<uint4*>(&As[0][(r << 6) + (cs << 3)]) = va;
        const uint4 vb = *reinterpret_cast<const uint4*>(wprojT + ((size_t)(nrow0 + r) << 8) + (c << 3));
        *reinterpret_cast<uint4*>(&Bs[0][(r << 6) + (cs << 3)]) = vb;
    }
    __syncthreads();

    for (int s = 0; s < 4; ++s) {
        if (s < 3) {
            const int so = (s + 1) << 6;
            #pragma unroll
            for (int i = 0; i < 4; ++i) {
                const int chunk = (i << 8) + tid;
                const int r = chunk >> 3, c = chunk & 7;
                const int cs = c ^ (r & 7);
                const uint4 va = *reinterpret_cast<const uint4*>(Ob + ((mrow0 + r) << 8) + so + (c << 3));
                *reinterpret_cast<uint4*>(&As[buf ^ 1][(r << 6) + (cs << 3)]) = va;
                const uint4 vb = *reinterpret_cast<const uint4*>(wprojT + ((size_t)(nrow0 + r) << 8) + so + (c << 3));
                *reinterpret_cast<uint4*>(&Bs[buf ^ 1][(r << 6) + (cs << 3)]) = vb;
            }
        }
        #pragma unroll
        for (int kk = 0; kk < 2; ++kk) {
            short8 aF[4], bF[4];
            #pragma unroll
            for (int i = 0; i < 4; ++i) {
                const int rA = (wr << 6) + (i << 4) + q16;
                const int cA = ((kk << 2) + g) ^ (rA & 7);
                aF[i] = *reinterpret_cast<const short8*>(&As[buf][(rA << 6) + (cA << 3)]);
                const int rB = (wc << 6) + (i << 4) + q16;
                const int cB = ((kk << 2) + g) ^ (rB & 7);
                bF[i] = *reinterpret_cast<const short8*>(&Bs[buf][(rB << 6) + (cB << 3)]);
            }
            #pragma unroll
            for (int i = 0; i < 4; ++i)
                #pragma unroll
                for (int j = 0; j < 4; ++j)
                    acc[i][j] = MFMA(aF[i], bF[j], acc[i][j]);
        }
        __syncthreads();
        buf ^= 1;
    }

    // epilogue: rows are spatial order -> direct coalesced store
    #pragma unroll
    for (int j = 0; j < 4; ++j) {
        const int coln = nrow0 + (wc << 6) + (j << 4) + q16;
        const float bp = bproj[coln];
        #pragma unroll
        for (int i = 0; i < 4; ++i) {
            const size_t row = mrow0 + (wr << 6) + (i << 4) + (g << 2);
            #pragma unroll
            for (int rr = 0; rr < 4; ++rr)
                out[((row + rr) << 8) + coln] = acc[i][j][rr] + bp;
        }
    }
}

extern "C" void kernel_launch(void* const* d_in, const int* in_sizes, int n_in,
                              void* d_out, int out_size, void* d_ws, size_t ws_size,
                              hipStream_t stream) {
    const float* x     = (const float*)d_in[0];
    const float* wqkv  = (const float*)d_in[1];
    const float* bqkv  = (const float*)d_in[2];
    const float* wproj = (const float*)d_in[3];
    const float* bproj = (const float*)d_in[4];
    float* out = (float*)d_out;
    unsigned short* wT = (unsigned short*)d_ws;

    prep_w<<<1024, 256, 0, stream>>>(wqkv, wproj, wT);
    unsigned short* Ob = wT + 262144;   // byte offset 524288
    attn_qkv<<<8192, 256, 0, stream>>>(x, bqkv, wT, Ob);
    proj_gemm<<<4096, 256, 0, stream>>>(Ob, wT + 196608, bproj, out);
}

// Round 14
// 298.495 us; speedup vs baseline: 1.5799x; 1.0373x over previous
//
#include <hip/hip_runtime.h>
#include <hip/hip_bf16.h>

typedef __attribute__((ext_vector_type(8))) short short8;
typedef __attribute__((ext_vector_type(4))) short short4v;
typedef __attribute__((ext_vector_type(4))) float f32x4;

#define MFMA(a, b, c) __builtin_amdgcn_mfma_f32_16x16x32_bf16(a, b, c, 0, 0, 0)
// XOR-swizzled [64][256] bf16 LDS index (8-elem granule)
#define XS(t, c) (((t) << 8) + ((c) ^ (((t) & 7) << 3)))

extern "C" __device__ float __ocml_native_exp2_f32(float);   // bare v_exp_f32
#define EXP2(x) __ocml_native_exp2_f32(x)

__device__ __forceinline__ unsigned int pk2(float lo, float hi) {
    union { __hip_bfloat162 h2; unsigned int u; } cv;
    cv.h2 = __float22bfloat162_rn(make_float2(lo, hi));
    return cv.u;
}

__device__ __forceinline__ unsigned short f2bf1(float f) {
    unsigned int u = __float_as_uint(f);
    u += 0x7FFFu + ((u >> 16) & 1u);
    return (unsigned short)(u >> 16);
}

__device__ __forceinline__ short4v u2s4(uint2 p) {
    union { uint2 u; short4v s; } t; t.u = p; return t.s;
}

#if __has_builtin(__builtin_amdgcn_mfma_f32_16x16x16bf16_1k)
__device__ __forceinline__ f32x4 mfma16(uint2 a, uint2 b, f32x4 c) {
    return __builtin_amdgcn_mfma_f32_16x16x16bf16_1k(u2s4(a), u2s4(b), c, 0, 0, 0);
}
#else
__device__ __forceinline__ short8 zfrag(uint2 p) {
    union { unsigned int u[4]; short8 s; } t;
    t.u[0] = p.x; t.u[1] = p.y; t.u[2] = 0u; t.u[3] = 0u;
    return t.s;
}
__device__ __forceinline__ f32x4 mfma16(uint2 a, uint2 b, f32x4 c) {
    return MFMA(zfrag(a), zfrag(b), c);
}
#endif

#define SCLF 0.25500566631879443f   // (1/sqrt(32)) * log2(e)

// d_ws layout (elements of unsigned short):
//  [0 .. 196608)    wpk: QKV weights in MFMA-FRAGMENT order; W_q PRE-SCALED by SCLF:
//                   frag f = ((m*8+h)*2+dt)*8+ks, elem = f*512 + lane*8 + j
//                   value = w_qkv[k=ks*32+(lane>>4)*8+j][n=m*256+h*32+dt*16+(lane&15)]
//  [196608..262144) wprojT [256][256]  (wprojT[n][k] = w_proj[k][n])
//  [262144 .. )     Ob bf16 [262144 tok (SPATIAL order)][256 ch]
__global__ void prep_w(const float* __restrict__ wqkv, const float* __restrict__ wproj,
                       unsigned short* __restrict__ wT) {
    int idx = blockIdx.x * 256 + threadIdx.x;   // 0..262143
    if (idx < 196608) {
        const int frag   = idx >> 9;        // 0..383
        const int within = idx & 511;
        const int lane = within >> 3, j = within & 7;
        const int ks = frag & 7;
        const int dt = (frag >> 3) & 1;
        const int hh = (frag >> 4) & 7;
        const int m  = frag >> 7;
        const int n = m * 256 + hh * 32 + dt * 16 + (lane & 15);
        const int k = ks * 32 + ((lane >> 4) << 3) + j;
        float v = wqkv[k * 768 + n];
        if (m == 0) v *= SCLF;              // fold softmax scale*log2e into W_q
        wT[idx] = f2bf1(v);
    } else {
        const int r = idx - 196608;
        const int n = r >> 8, k = r & 255;
        wT[idx] = f2bf1(wproj[(k << 8) + n]);
    }
}

// ============ Kernel A: per (window, head-quad) QKV + attention ============
// Single-xf-pass QKV; bias folded into MFMA C-init; q-scale folded into W_q;
// exp2 via bare v_exp_f32. Peak live ~100 regs < 128 cap (bounds(256,2)).
__global__ __launch_bounds__(256, 2)
void attn_qkv(const float* __restrict__ x,
              const float* __restrict__ bqkv,
              const unsigned short* __restrict__ wpk,
              unsigned short* __restrict__ Ob)
{
    __shared__ unsigned short smem[64 * 256];   // 32 KiB: x only

    const int tid  = threadIdx.x;
    const int wid  = tid >> 6;
    const int lane = tid & 63;
    const int g    = lane >> 4;
    const int q16  = lane & 15;

    // XCD-pairing swizzle: two head-quad blocks of a window on the same XCD.
    const int bid  = blockIdx.x;
    const int xcd  = bid & 7;
    const int q    = bid >> 3;
    const int widx = xcd * 512 + (q >> 1);
    const int hq   = (q & 1) << 2;     // head-quad base (0 or 4)
    const int h    = hq + wid;         // this wave's head

    const int b  = widx >> 10;
    const int wh = (widx >> 5) & 31;
    const int ww = widx & 31;

    // ---- stage x window -> LDS bf16 (swizzled) ----
    {
        const int t  = tid >> 2;           // token 0..63
        const int c0 = (tid & 3) << 3;     // channel base
        const int hr = (wh << 3) + (t >> 3);
        const int wc = (ww << 3) + (t & 7);
        const float* rowp = x + (((size_t)b * 256 + hr) * 256 + wc) * 256;
        #pragma unroll
        for (int u = 0; u < 8; ++u) {
            const int c = c0 + (u << 5);
            const float4 f0 = *reinterpret_cast<const float4*>(rowp + c);
            const float4 f1 = *reinterpret_cast<const float4*>(rowp + c + 4);
            union { unsigned int u4[4]; short8 s; } pv;
            pv.u4[0] = pk2(f0.x, f0.y); pv.u4[1] = pk2(f0.z, f0.w);
            pv.u4[2] = pk2(f1.x, f1.y); pv.u4[3] = pk2(f1.z, f1.w);
            *reinterpret_cast<short8*>(&smem[XS(t, c)]) = pv.s;
        }
    }
    __syncthreads();   // the ONLY barrier in this kernel

    const unsigned short* wh0 = wpk + ((size_t)h << 13);   // head base; m stride 8<<13
    const int loff = lane << 3;

    // ===== merged QKV, single xf pass per half; bias in C-init =====
    // pq/pkk: {q,k}[tok=tt*16+q16][d=dt*16+g*4+{0..3}]   (D = W·x^T + bias), q pre-scaled
    // pv2   :  v[tok=tt*16+g*4+{0..3}][d=dt*16+q16]      (D = x·W + bias)
    uint2 pq[2][4], pkk[2][4], pv2[2][4];
    #pragma unroll
    for (int half = 0; half < 2; ++half) {
        f32x4 acc[3][2][2];
        #pragma unroll
        for (int dt = 0; dt < 2; ++dt) {
            const float4 bbq = *reinterpret_cast<const float4*>(bqkv + h * 32 + dt * 16 + (g << 2));
            const float4 bbk = *reinterpret_cast<const float4*>(bqkv + 256 + h * 32 + dt * 16 + (g << 2));
            const float bv = bqkv[512 + h * 32 + dt * 16 + q16];
            const f32x4 iq = {bbq.x * SCLF, bbq.y * SCLF, bbq.z * SCLF, bbq.w * SCLF};
            const f32x4 ik = {bbk.x, bbk.y, bbk.z, bbk.w};
            const f32x4 iv = {bv, bv, bv, bv};
            #pragma unroll
            for (int t2 = 0; t2 < 2; ++t2) {
                acc[0][dt][t2] = iq; acc[1][dt][t2] = ik; acc[2][dt][t2] = iv;
            }
        }

        #pragma unroll
        for (int ks = 0; ks < 8; ++ks) {
            const int kc = ks << 5;
            short8 xf[2];
            #pragma unroll
            for (int t2 = 0; t2 < 2; ++t2)
                xf[t2] = *reinterpret_cast<const short8*>(
                    &smem[XS(((half << 1) + t2) * 16 + q16, kc + (g << 3))]);
            #pragma unroll
            for (int m = 0; m < 3; ++m) {
                #pragma unroll
                for (int dt = 0; dt < 2; ++dt) {
                    const short8 wf = *reinterpret_cast<const short8*>(
                        wh0 + (((size_t)m << 16) | (((dt << 3) + ks) << 9)) + loff);
                    #pragma unroll
                    for (int t2 = 0; t2 < 2; ++t2)
                        acc[m][dt][t2] = (m < 2) ? MFMA(wf, xf[t2], acc[m][dt][t2])
                                                 : MFMA(xf[t2], wf, acc[m][dt][t2]);
                }
            }
        }
        // pack (no bias/scale math left)
        #pragma unroll
        for (int dt = 0; dt < 2; ++dt) {
            #pragma unroll
            for (int t2 = 0; t2 < 2; ++t2) {
                const int tt = (half << 1) + t2;
                const f32x4 aq = acc[0][dt][t2];
                pq[dt][tt]  = make_uint2(pk2(aq[0], aq[1]), pk2(aq[2], aq[3]));
                const f32x4 ak = acc[1][dt][t2];
                pkk[dt][tt] = make_uint2(pk2(ak[0], ak[1]), pk2(ak[2], ak[3]));
                const f32x4 av = acc[2][dt][t2];
                pv2[dt][tt] = make_uint2(pk2(av[0], av[1]), pk2(av[2], av[3]));
            }
        }
    }

    // ===== S^T = K·Q^T (K=16), exp2 (no max-sub), unnormalized P^T =====
    const f32x4 fz = {0.f, 0.f, 0.f, 0.f};
    uint2 ppk[4][4];   // [kt][qt]: P^T[key=kt*16+g*4+{0..3}][qtok=qt*16+q16]
    float inv4[4];
    #pragma unroll
    for (int qt = 0; qt < 4; ++qt) {
        f32x4 st[4];
        #pragma unroll
        for (int kt = 0; kt < 4; ++kt) st[kt] = fz;
        #pragma unroll
        for (int dt = 0; dt < 2; ++dt)
            #pragma unroll
            for (int kt = 0; kt < 4; ++kt)
                st[kt] = mfma16(pkk[dt][kt], pq[dt][qt], st[kt]);
        float sum = 0.f;
        #pragma unroll
        for (int kt = 0; kt < 4; ++kt) {
            const float e0 = EXP2(st[kt][0]), e1 = EXP2(st[kt][1]);
            const float e2 = EXP2(st[kt][2]), e3 = EXP2(st[kt][3]);
            sum += (e0 + e1) + (e2 + e3);
            ppk[kt][qt] = make_uint2(pk2(e0, e1), pk2(e2, e3));
        }
        sum += __shfl_xor(sum, 16);
        sum += __shfl_xor(sum, 32);
        inv4[qt] = 1.f / sum;
    }

    // ===== O^T = V^T·P^T (K=16) =====
    f32x4 ot[2][4];    // lane: O[tok=tt*16+q16][d=h*32+dt*16+g*4+r]
    #pragma unroll
    for (int dt = 0; dt < 2; ++dt)
        #pragma unroll
        for (int tt = 0; tt < 4; ++tt) ot[dt][tt] = fz;
    #pragma unroll
    for (int kt = 0; kt < 4; ++kt)
        #pragma unroll
        for (int tt = 0; tt < 4; ++tt)
            #pragma unroll
            for (int dt = 0; dt < 2; ++dt)
                ot[dt][tt] = mfma16(pv2[dt][kt], ppk[kt][tt], ot[dt][tt]);

    // ===== direct global write of O (spatial row order) =====
    #pragma unroll
    for (int tt = 0; tt < 4; ++tt) {
        const float iv = inv4[tt];
        const int tok = tt * 16 + q16;
        const size_t srow = (((size_t)(b << 8) + (wh << 3) + (tok >> 3)) << 8)
                            + (ww << 3) + (tok & 7);
        unsigned short* drow = Ob + (srow << 8) + h * 32 + (g << 2);
        #pragma unroll
        for (int dt = 0; dt < 2; ++dt) {
            const uint2 pv = make_uint2(pk2(ot[dt][tt][0] * iv, ot[dt][tt][1] * iv),
                                        pk2(ot[dt][tt][2] * iv, ot[dt][tt][3] * iv));
            *reinterpret_cast<uint2*>(drow + dt * 16) = pv;
        }
    }
}

// ============ Kernel B: proj GEMM  out = O @ wproj + bias ============
__global__ __launch_bounds__(256, 2)
void proj_gemm(const unsigned short* __restrict__ Ob,
               const unsigned short* __restrict__ wprojT,
               const float* __restrict__ bproj,
               float* __restrict__ out)
{
    __shared__ unsigned short As[2][128 * 64];   // 16KB each
    __shared__ unsigned short Bs[2][128 * 64];

    const int tid  = threadIdx.x;
    const int wid  = tid >> 6;
    const int lane = tid & 63;
    const int g    = lane >> 4;
    const int q16  = lane & 15;
    const int wr   = wid >> 1, wc = wid & 1;

    // XCD-pairing swizzle: (mt, nt=0/1) pair shares the A-tile on one XCD
    const int bid = blockIdx.x;
    const int q   = bid >> 3;
    const int mt  = (bid & 7) * 256 + (q >> 1);
    const int nt  = q & 1;
    const size_t mrow0 = (size_t)mt << 7;
    const int nrow0 = nt << 7;

    const f32x4 fz = {0.f, 0.f, 0.f, 0.f};
    f32x4 acc[4][4];
    #pragma unroll
    for (int i = 0; i < 4; ++i)
        #pragma unroll
        for (int j = 0; j < 4; ++j) acc[i][j] = fz;

    int buf = 0;
    #pragma unroll
    for (int i = 0; i < 4; ++i) {
        const int chunk = (i << 8) + tid;
        const int r = chunk >> 3, c = chunk & 7;
        const int cs = c ^ (r & 7);
        const uint4 va = *reinterpret_cast<const uint4*>(Ob + ((mrow0 + r) << 8) + (c << 3));
        *reinterpret_cast<uint4*>(&As[0][(r << 6) + (cs << 3)]) = va;
        const uint4 vb = *reinterpret_cast<const uint4*>(wprojT + ((size_t)(nrow0 + r) << 8) + (c << 3));
        *reinterpret_cast<uint4*>(&Bs[0][(r << 6) + (cs << 3)]) = vb;
    }
    __syncthreads();

    for (int s = 0; s < 4; ++s) {
        if (s < 3) {
            const int so = (s + 1) << 6;
            #pragma unroll
            for (int i = 0; i < 4; ++i) {
                const int chunk = (i << 8) + tid;
                const int r = chunk >> 3, c = chunk & 7;
                const int cs = c ^ (r & 7);
                const uint4 va = *reinterpret_cast<const uint4*>(Ob + ((mrow0 + r) << 8) + so + (c << 3));
                *reinterpret_cast<uint4*>(&As[buf ^ 1][(r << 6) + (cs << 3)]) = va;
                const uint4 vb = *reinterpret_cast<const uint4*>(wprojT + ((size_t)(nrow0 + r) << 8) + so + (c << 3));
                *reinterpret_cast<uint4*>(&Bs[buf ^ 1][(r << 6) + (cs << 3)]) = vb;
            }
        }
        #pragma unroll
        for (int kk = 0; kk < 2; ++kk) {
            short8 aF[4], bF[4];
            #pragma unroll
            for (int i = 0; i < 4; ++i) {
                const int rA = (wr << 6) + (i << 4) + q16;
                const int cA = ((kk << 2) + g) ^ (rA & 7);
                aF[i] = *reinterpret_cast<const short8*>(&As[buf][(rA << 6) + (cA << 3)]);
                const int rB = (wc << 6) + (i << 4) + q16;
                const int cB = ((kk << 2) + g) ^ (rB & 7);
                bF[i] = *reinterpret_cast<const short8*>(&Bs[buf][(rB << 6) + (cB << 3)]);
            }
            #pragma unroll
            for (int i = 0; i < 4; ++i)
                #pragma unroll
                for (int j = 0; j < 4; ++j)
                    acc[i][j] = MFMA(aF[i], bF[j], acc[i][j]);
        }
        __syncthreads();
        buf ^= 1;
    }

    // epilogue: rows are spatial order -> direct coalesced store
    #pragma unroll
    for (int j = 0; j < 4; ++j) {
        const int coln = nrow0 + (wc << 6) + (j << 4) + q16;
        const float bp = bproj[coln];
        #pragma unroll
        for (int i = 0; i < 4; ++i) {
            const size_t row = mrow0 + (wr << 6) + (i << 4) + (g << 2);
            #pragma unroll
            for (int rr = 0; rr < 4; ++rr)
                out[((row + rr) << 8) + coln] = acc[i][j][rr] + bp;
        }
    }
}

extern "C" void kernel_launch(void* const* d_in, const int* in_sizes, int n_in,
                              void* d_out, int out_size, void* d_ws, size_t ws_size,
                              hipStream_t stream) {
    const float* x     = (const float*)d_in[0];
    const float* wqkv  = (const float*)d_in[1];
    const float* bqkv  = (const float*)d_in[2];
    const float* wproj = (const float*)d_in[3];
    const float* bproj = (const float*)d_in[4];
    float* out = (float*)d_out;
    unsigned short* wT = (unsigned short*)d_ws;

    prep_w<<<1024, 256, 0, stream>>>(wqkv, wproj, wT);
    unsigned short* Ob = wT + 262144;   // byte offset 524288
    attn_qkv<<<8192, 256, 0, stream>>>(x, bqkv, wT, Ob);
    proj_gemm<<<4096, 256, 0, stream>>>(Ob, wT + 196608, bproj, out);
}